// Round 8
// baseline (763.147 us; speedup 1.0000x reference)
//
#include <hip/hip_runtime.h>
#include <hip/hip_bf16.h>
#include <cstdint>

#define B_ 8
#define N_ 4096
#define CIN_ 64
#define COUT_ 128
#define R_ 32
#define R3_ 32768
#define GROUPS_ 8
#define EPS_ 1e-5f

typedef float f32x4 __attribute__((ext_vector_type(4)));
typedef __bf16 bf16x8 __attribute__((ext_vector_type(8)));
typedef unsigned short ushort8x __attribute__((ext_vector_type(8)));

static __device__ __forceinline__ unsigned short f2b(float f) {
    uint32_t u = __float_as_uint(f);
    uint32_t r = (u + 0x7fffu + ((u >> 16) & 1u)) >> 16;  // RNE
    return (unsigned short)r;
}
static __device__ __forceinline__ float b2f(unsigned short u) {
    return __uint_as_float(((uint32_t)u) << 16);
}
// fast swish via v_exp_f32 + v_rcp_f32 (bf16-accurate)
static __device__ __forceinline__ float fswish(float s) {
    return s * __builtin_amdgcn_rcpf(1.0f + __expf(-s));
}

// ---------------------------------------------------------------- batch stats
__global__ void k_batch_stats(const float* __restrict__ coords, float* __restrict__ bstats) {
    int b = blockIdx.x;
    int tid = threadIdx.x;
    __shared__ float rb[256];
    __shared__ float smean[3];
    const float* cb = coords + (size_t)b * N_ * 3;
    float sx = 0.f, sy = 0.f, sz = 0.f;
    for (int n = tid; n < N_; n += 256) {
        sx += cb[n * 3 + 0];
        sy += cb[n * 3 + 1];
        sz += cb[n * 3 + 2];
    }
    float vals[3] = {sx, sy, sz};
    for (int k = 0; k < 3; ++k) {
        rb[tid] = vals[k];
        __syncthreads();
        for (int s = 128; s > 0; s >>= 1) {
            if (tid < s) rb[tid] += rb[tid + s];
            __syncthreads();
        }
        if (tid == 0) smean[k] = rb[0] / (float)N_;
        __syncthreads();
    }
    float mx = smean[0], my = smean[1], mz = smean[2];
    float m2 = 0.f;
    for (int n = tid; n < N_; n += 256) {
        float dx = cb[n * 3 + 0] - mx, dy = cb[n * 3 + 1] - my, dz = cb[n * 3 + 2] - mz;
        m2 = fmaxf(m2, dx * dx + dy * dy + dz * dz);
    }
    rb[tid] = m2;
    __syncthreads();
    for (int s = 128; s > 0; s >>= 1) {
        if (tid < s) rb[tid] = fmaxf(rb[tid], rb[tid + s]);
        __syncthreads();
    }
    if (tid == 0) {
        bstats[b * 4 + 0] = mx;
        bstats[b * 4 + 1] = my;
        bstats[b * 4 + 2] = mz;
        bstats[b * 4 + 3] = 2.0f * sqrtf(rb[0]);
    }
}

// -------------------------------------------------- per-point coords + counts
__global__ void k_points(const float* __restrict__ coords, const float* __restrict__ bstats,
                         float* __restrict__ ncoords, int* __restrict__ flatidx,
                         float* __restrict__ cnt) {
    int idx = blockIdx.x * 256 + threadIdx.x;  // b*N + n
    int b = idx >> 12, n = idx & (N_ - 1);
    float scale = bstats[b * 4 + 3];
    int vi[3];
    for (int k = 0; k < 3; ++k) {
        float c = coords[((size_t)b * N_ + n) * 3 + k] - bstats[b * 4 + k];
        float nc = fminf(fmaxf((c / scale + 0.5f) * (float)R_, 0.0f), (float)(R_ - 1));
        ncoords[((size_t)b * N_ + n) * 3 + k] = nc;
        vi[k] = (int)rintf(nc);  // round half-to-even, matches jnp.round
    }
    int flat = (vi[0] * R_ + vi[1]) * R_ + vi[2];
    flatidx[idx] = flat;
    atomicAdd(&cnt[(size_t)b * R3_ + flat], 1.0f);
}

// ------------------------------------------------------------- scatter (sum)
__global__ void k_scatter(const float* __restrict__ feat, const int* __restrict__ flatidx,
                          float* __restrict__ vox, int b0) {
    int bid = blockIdx.x;               // CB * 64ci * 16 chunks
    int nch = bid & 15, ci = (bid >> 4) & 63, bl = bid >> 10;
    int b = b0 + bl;
    int n = nch * 256 + threadIdx.x;
    float v = feat[((size_t)b * CIN_ + ci) * N_ + n];
    int flat = flatidx[b * N_ + n];
    atomicAdd(&vox[((size_t)bl * R3_ + flat) * CIN_ + ci], v);
}

// ----------------------------------- divide by counts, fp32 -> bf16 channels-last
__global__ void k_divide(const float* __restrict__ vox, const float* __restrict__ cnt,
                         unsigned short* __restrict__ gA, int b0) {
    size_t idx8 = (size_t)blockIdx.x * 256 + threadIdx.x;  // < cb*R3*8
    size_t voxel = idx8 >> 3;                              // bl*R3 + flat
    float c = cnt[(size_t)b0 * R3_ + voxel];
    float s = 1.0f / fmaxf(c, 1.0f);
    const float4* v4 = (const float4*)vox;
    float4 a = v4[idx8 * 2], b = v4[idx8 * 2 + 1];
    ushort8x o;
    o[0] = f2b(a.x * s); o[1] = f2b(a.y * s); o[2] = f2b(a.z * s); o[3] = f2b(a.w * s);
    o[4] = f2b(b.x * s); o[5] = f2b(b.y * s); o[6] = f2b(b.z * s); o[7] = f2b(b.w * s);
    ((ushort8x*)gA)[idx8] = o;
}

// ---------------------------------------- features fp32 -> bf16 (chunk-local)
__global__ void k_feat2b(const float* __restrict__ f, unsigned short* __restrict__ fb, int b0) {
    size_t i8 = (size_t)blockIdx.x * 256 + threadIdx.x;  // < CB*64*N/8
    const float4* s = (const float4*)(f + (size_t)b0 * CIN_ * N_);
    float4 a = s[i8 * 2], b = s[i8 * 2 + 1];
    ushort8x o;
    o[0] = f2b(a.x); o[1] = f2b(a.y); o[2] = f2b(a.z); o[3] = f2b(a.w);
    o[4] = f2b(b.x); o[5] = f2b(b.y); o[6] = f2b(b.z); o[7] = f2b(b.w);
    ((ushort8x*)fb)[i8] = o;
}

// --------------------- weight pack for 16x16x32 MFMA B-fragments
// wp element e = (((t*KC + kc)*8 + ct)*64 + l)*8 + j  holds
//   w[co = ct*16 + (l&15)][ci = kc*32 + (l>>4)*8 + j][t],  w layout [128][Cin][taps]
__global__ void k_wpack16(const float* __restrict__ w, unsigned short* __restrict__ wp,
                          int Cin, int taps) {
    int e = blockIdx.x * 256 + threadIdx.x;
    int total = taps * Cin * 128;
    if (e >= total) return;
    int KC = Cin / 32;
    int j = e & 7;
    int l = (e >> 3) & 63;
    int rest = e >> 9;
    int ct = rest & 7;
    int stepk = rest >> 3;  // t*KC + kc
    int kc = stepk % KC;
    int t = stepk / KC;
    int co = ct * 16 + (l & 15);
    int ci = kc * 32 + (l >> 4) * 8 + j;
    wp[e] = f2b(w[((size_t)co * Cin + ci) * taps + t]);
}

// --------------- GN apply + swish in-place on bf16 grid, A/B from raw stats
__global__ void k_gnswish(unsigned short* __restrict__ g, const float* __restrict__ stats,
                          const float* __restrict__ gamma, const float* __restrict__ beta,
                          int b0) {
    size_t idx8 = (size_t)blockIdx.x * 256 + threadIdx.x;  // < cb*R3*16
    int c0 = (int)(idx8 & 15) * 8;
    int b = b0 + (int)(idx8 >> 19);  // R3*128/8 = 2^19
    int grp = c0 >> 4;
    const float cntv = 16.0f * R3_;
    float mean = stats[(b * 8 + grp) * 2 + 0] / cntv;
    float var = stats[(b * 8 + grp) * 2 + 1] / cntv - mean * mean;
    float inv = rsqrtf(var + EPS_);
    ushort8x v = ((ushort8x*)g)[idx8];
#pragma unroll
    for (int k = 0; k < 8; ++k) {
        float A = gamma[c0 + k] * inv;
        float Bc = beta[c0 + k] - mean * A;
        v[k] = f2b(fswish(A * b2f(v[k]) + Bc));
    }
    ((ushort8x*)g)[idx8] = v;
}

// --------------------- implicit-GEMM 3x3x3 conv via bf16 MFMA 16x16x32
// in : [cb, R3, CIN] bf16 channels-last; out: [cb, R3, 128] bf16 (+bias); GN stats fused.
// block: 128 threads = 2 waves, covers (bl, x, 4 y-cols) = 128 voxels x 128 co.
// wave (zt = wave id): M = 4 y-cols x 16 z (4 M-tiles), N = 128 co (8 N-tiles).
//   per (t,kc) step: 8 B glb loads (each reused 4x in regs) + 4 A ds_reads
//   (each reused 8x) + 32 MFMAs  ->  B L1 traffic 256 B/MFMA (~53 B/cyc at peak).
template <int CIN>
__global__ __launch_bounds__(128, 2) void k_conv16(
    const unsigned short* __restrict__ in, const unsigned short* __restrict__ wp,
    const float* __restrict__ bias, unsigned short* __restrict__ out,
    float* __restrict__ stats, int b0) {
    constexpr int KC = CIN / 32;
    constexpr int S = CIN + 8;  // row stride (bf16), 16B-aligned
    __shared__ unsigned short abuf[6 * 34 * S];
    __shared__ float s_sum[8], s_sq[8];
    int tid = threadIdx.x;
    int bid = blockIdx.x;
    int yg = bid & 7, x = (bid >> 3) & 31, bl = bid >> 8;
    int y0 = yg * 4;
    int lane = tid & 63, zt = tid >> 6;  // wave = z-half
    int mrow = lane & 15, quad = lane >> 4;

    if (tid < 8) { s_sum[tid] = 0.f; s_sq[tid] = 0.f; }
    // zero z-halo rows 0 and 33 for all 6 y-columns
    for (int i = tid; i < 6 * 2 * (CIN / 8); i += 128) {
        int cy = i / (2 * (CIN / 8));
        int r = i - cy * (2 * (CIN / 8));
        int hz = (r >= (CIN / 8)) ? 33 : 0;
        int c8 = r % (CIN / 8);
        ushort8x zz = {0, 0, 0, 0, 0, 0, 0, 0};
        *(ushort8x*)&abuf[(cy * 34 + hz) * S + c8 * 8] = zz;
    }

    float bv[8];
#pragma unroll
    for (int ct = 0; ct < 8; ++ct) bv[ct] = bias[ct * 16 + mrow];
    f32x4 acc[4][8];  // [yc][ct]
#pragma unroll
    for (int yc = 0; yc < 4; ++yc)
#pragma unroll
        for (int ct = 0; ct < 8; ++ct) {
            acc[yc][ct][0] = bv[ct]; acc[yc][ct][1] = bv[ct];
            acc[yc][ct][2] = bv[ct]; acc[yc][ct][3] = bv[ct];
        }

    for (int xxi = 0; xxi < 3; ++xxi) {
        int xx = x + xxi - 1;
        if (xx < 0 || xx >= 32) continue;  // zero-pad: drop dx taps (block-uniform)
        __syncthreads();
        // stage 6 y-columns (32z x CIN) into rows 1..32 (pure copy)
        for (int i = tid; i < 6 * 32 * (CIN / 8); i += 128) {
            int cy = i / (32 * (CIN / 8));
            int r = i - cy * (32 * (CIN / 8));
            int z = r / (CIN / 8), c8 = r - z * (CIN / 8);
            int yy = y0 - 1 + cy;
            ushort8x v = {0, 0, 0, 0, 0, 0, 0, 0};
            if (yy >= 0 && yy < 32)
                v = *(const ushort8x*)&in[((size_t)bl * R3_ + xx * 1024 + yy * 32 + z) * CIN + c8 * 8];
            *(ushort8x*)&abuf[(cy * 34 + z + 1) * S + c8 * 8] = v;
        }
        __syncthreads();

        for (int dy3 = 0; dy3 < 3; ++dy3) {
            for (int dz = 0; dz < 3; ++dz) {
                int t = (xxi * 3 + dy3) * 3 + dz;
#pragma unroll
                for (int kc = 0; kc < KC; ++kc) {
                    const unsigned short* wbase =
                        wp + ((size_t)((t * KC + kc) * 8) * 64 + lane) * 8;
                    bf16x8 bfr[8];
#pragma unroll
                    for (int ct = 0; ct < 8; ++ct)
                        bfr[ct] = *(const bf16x8*)(wbase + ct * 512);
#pragma unroll
                    for (int yc = 0; yc < 4; ++yc) {
                        int cy = yc + dy3;
                        bf16x8 a = *(const bf16x8*)
                            &abuf[(cy * 34 + zt * 16 + mrow + dz) * S + kc * 32 + quad * 8];
#pragma unroll
                        for (int ct = 0; ct < 8; ++ct)
                            acc[yc][ct] = __builtin_amdgcn_mfma_f32_16x16x32_bf16(
                                a, bfr[ct], acc[yc][ct], 0, 0, 0);
                    }
                }
            }
        }
    }

    // store bf16 + GN stats. C/D: co = ct*16 + mrow, z = zt*16 + quad*4 + r
    float lsum[8] = {0.f, 0.f, 0.f, 0.f, 0.f, 0.f, 0.f, 0.f};
    float lsq[8] = {0.f, 0.f, 0.f, 0.f, 0.f, 0.f, 0.f, 0.f};
#pragma unroll
    for (int yc = 0; yc < 4; ++yc) {
        int y = y0 + yc;
        unsigned short* obase = out + ((size_t)bl * R3_ + x * 1024 + y * 32) * 128;
#pragma unroll
        for (int ct = 0; ct < 8; ++ct) {
            int co = ct * 16 + mrow;
#pragma unroll
            for (int r = 0; r < 4; ++r) {
                int z = zt * 16 + quad * 4 + r;
                float vv = acc[yc][ct][r];
                obase[(size_t)z * 128 + co] = f2b(vv);
                lsum[ct] += vv;
                lsq[ct] += vv * vv;
            }
        }
    }
    // group of co = ct*16 + mrow is exactly ct -> whole-wave reduce per ct
#pragma unroll
    for (int ct = 0; ct < 8; ++ct) {
        float s = lsum[ct], q = lsq[ct];
#pragma unroll
        for (int off = 32; off >= 1; off >>= 1) {
            s += __shfl_xor(s, off);
            q += __shfl_xor(q, off);
        }
        if (lane == 0) {
            atomicAdd(&s_sum[ct], s);
            atomicAdd(&s_sq[ct], q);
        }
    }
    __syncthreads();
    if (tid < 8) {
        int b = b0 + bl;
        atomicAdd(&stats[((size_t)b * 8 + tid) * 2 + 0], s_sum[tid]);
        atomicAdd(&stats[((size_t)b * 8 + tid) * 2 + 1], s_sq[tid]);
    }
}

// ------------------- point transform 64->128 via MFMA, pf bf16 [n][co], + stats
__global__ __launch_bounds__(256) void k_point_mfma(
    const unsigned short* __restrict__ featb, const unsigned short* __restrict__ wp,
    const float* __restrict__ bias, unsigned short* __restrict__ pf,
    float* __restrict__ stats, int b0) {
    __shared__ __align__(16) unsigned short ALds[256 * 72];
    int tid = threadIdx.x;
    int bid = blockIdx.x;
    int bl = bid >> 4;
    int n0 = (bid & 15) * 256;
    int b = b0 + bl;
    int lane = tid & 63, wv = tid >> 6;
    int nh = wv & 1, ch = wv >> 1;
    int mrow = lane & 15, quad = lane >> 4;

    {
        int c0 = (tid >> 5) * 8;
        int nl = tid & 31;
        for (int u = 0; u < 8; ++u) {
            int n = u * 32 + nl;
            ushort8x v;
#pragma unroll
            for (int k = 0; k < 8; ++k)
                v[k] = featb[((size_t)(bl * 64 + c0 + k)) * N_ + n0 + n];
            *(ushort8x*)&ALds[n * 72 + c0] = v;
        }
    }

    bf16x8 bfr[2][4];
#pragma unroll
    for (int kc = 0; kc < 2; ++kc)
#pragma unroll
        for (int ct = 0; ct < 4; ++ct)
            bfr[kc][ct] = *(const bf16x8*)&wp[((size_t)((kc * 8) + ch * 4 + ct) * 64 + lane) * 8];

    float bv[4];
#pragma unroll
    for (int ct = 0; ct < 4; ++ct) bv[ct] = bias[ch * 64 + ct * 16 + mrow];
    f32x4 acc[8][4];
#pragma unroll
    for (int mt = 0; mt < 8; ++mt)
#pragma unroll
        for (int ct = 0; ct < 4; ++ct) {
            acc[mt][ct][0] = bv[ct]; acc[mt][ct][1] = bv[ct];
            acc[mt][ct][2] = bv[ct]; acc[mt][ct][3] = bv[ct];
        }

    __syncthreads();
#pragma unroll
    for (int kc = 0; kc < 2; ++kc) {
#pragma unroll
        for (int mt = 0; mt < 8; ++mt) {
            bf16x8 a = *(const bf16x8*)
                &ALds[(nh * 128 + mt * 16 + mrow) * 72 + kc * 32 + quad * 8];
#pragma unroll
            for (int ct = 0; ct < 4; ++ct)
                acc[mt][ct] = __builtin_amdgcn_mfma_f32_16x16x32_bf16(
                    a, bfr[kc][ct], acc[mt][ct], 0, 0, 0);
        }
    }

#pragma unroll
    for (int ct = 0; ct < 4; ++ct) {
        int co = ch * 64 + ct * 16 + mrow;
        float s = 0.f, q = 0.f;
#pragma unroll
        for (int mt = 0; mt < 8; ++mt) {
#pragma unroll
            for (int r = 0; r < 4; ++r) {
                int n = nh * 128 + mt * 16 + quad * 4 + r;
                float vv = acc[mt][ct][r];
                pf[((size_t)bl * N_ + n0 + n) * 128 + co] = f2b(vv);
                s += vv;
                q += vv * vv;
            }
        }
#pragma unroll
        for (int off = 32; off >= 1; off >>= 1) {
            s += __shfl_xor(s, off);
            q += __shfl_xor(q, off);
        }
        if (lane == 0) {
            int g = ch * 4 + ct;
            atomicAdd(&stats[((size_t)b * 8 + g) * 2 + 0], s);
            atomicAdd(&stats[((size_t)b * 8 + g) * 2 + 1], q);
        }
    }
}

// ------ trilinear devoxelize (GN2+swish fused per gather) + point GN/swish + add
__global__ __launch_bounds__(256) void k_final(
    const unsigned short* __restrict__ grid, const float* __restrict__ ncoords,
    const unsigned short* __restrict__ pf,
    const float* __restrict__ stats2, const float* __restrict__ g2g,
    const float* __restrict__ g2b,
    const float* __restrict__ statsPt, const float* __restrict__ pgg,
    const float* __restrict__ pgb,
    float* __restrict__ out, int b0) {
    __shared__ int sidx[32][8];
    __shared__ float swt[32][8];
    __shared__ float devt[32 * 129];
    int bid = blockIdx.x;
    int bl = bid >> 7;
    int b = b0 + bl;
    int n0 = (bid & 127) * 32;
    int tid = threadIdx.x;
    if (tid < 32) {
        int n = n0 + tid;
        const float* nc = ncoords + ((size_t)b * N_ + n) * 3;
        float fc[3] = {nc[0], nc[1], nc[2]};
        int i0[3], i1[3];
        float dd[3];
        for (int k = 0; k < 3; ++k) {
            float fl = floorf(fc[k]);
            i0[k] = (int)fl;
            i1[k] = min(i0[k] + 1, R_ - 1);
            dd[k] = fc[k] - fl;
        }
#pragma unroll
        for (int k = 0; k < 8; ++k) {
            int ix = (k >> 2) & 1, iy = (k >> 1) & 1, iz = k & 1;
            int xi = ix ? i1[0] : i0[0];
            int yi = iy ? i1[1] : i0[1];
            int zi = iz ? i1[2] : i0[2];
            sidx[tid][k] = (xi * R_ + yi) * R_ + zi;
            float wx = ix ? dd[0] : 1.0f - dd[0];
            float wy = iy ? dd[1] : 1.0f - dd[1];
            float wz = iz ? dd[2] : 1.0f - dd[2];
            swt[tid][k] = wx * wy * wz;
        }
    }
    __syncthreads();
    int co = tid & 127, pg = tid >> 7;
    int grp = co >> 4;
    const float ic2 = 1.0f / (16.0f * R3_);
    float mean2 = stats2[(b * 8 + grp) * 2 + 0] * ic2;
    float var2 = stats2[(b * 8 + grp) * 2 + 1] * ic2 - mean2 * mean2;
    float inv2 = rsqrtf(var2 + EPS_);
    float A2 = g2g[co] * inv2, B2 = g2b[co] - mean2 * A2;
    const float icp = 1.0f / (16.0f * N_);
    float meanp = statsPt[(b * 8 + grp) * 2 + 0] * icp;
    float varp = statsPt[(b * 8 + grp) * 2 + 1] * icp - meanp * meanp;
    float invp = rsqrtf(varp + EPS_);
    float Ap = pgg[co] * invp, Bp = pgb[co] - meanp * Ap;

    const unsigned short* gp = grid + (size_t)bl * R3_ * 128 + co;
    for (int p = pg; p < 32; p += 2) {
        float acc = 0.f;
#pragma unroll
        for (int k = 0; k < 8; ++k) {
            float s = A2 * b2f(gp[(size_t)sidx[p][k] * 128]) + B2;
            acc += swt[p][k] * fswish(s);
        }
        float xv = b2f(pf[((size_t)bl * N_ + n0 + p) * 128 + co]);
        devt[p * 129 + co] = acc + fswish(Ap * xv + Bp);
    }
    __syncthreads();
    int pp = tid & 31, cg = tid >> 5;
    float* op = out + (size_t)b * 128 * N_ + n0 + pp;
    for (int c = cg * 16; c < cg * 16 + 16; ++c)
        op[(size_t)c * N_] = devt[pp * 129 + c];
}

extern "C" void kernel_launch(void* const* d_in, const int* in_sizes, int n_in,
                              void* d_out, int out_size, void* d_ws, size_t ws_size,
                              hipStream_t stream) {
    const float* features = (const float*)d_in[0];
    const float* coords = (const float*)d_in[1];
    const float* c1w = (const float*)d_in[2];
    const float* c1b = (const float*)d_in[3];
    const float* g1g = (const float*)d_in[4];
    const float* g1b = (const float*)d_in[5];
    const float* c2w = (const float*)d_in[6];
    const float* c2b = (const float*)d_in[7];
    const float* g2g = (const float*)d_in[8];
    const float* g2b = (const float*)d_in[9];
    const float* ptw = (const float*)d_in[10];
    const float* ptb = (const float*)d_in[11];
    const float* pgg = (const float*)d_in[12];
    const float* pgb = (const float*)d_in[13];
    float* outp = (float*)d_out;

    size_t globals = ((size_t)B_ * R3_ * 4 + 255 & ~(size_t)255)        // cnt
                   + ((size_t)B_ * N_ * 3 * 4 + 255 & ~(size_t)255)     // ncoords
                   + ((size_t)B_ * N_ * 4 + 255 & ~(size_t)255)         // flatidx
                   + 256 + 2048                                         // bstats, statsAll
                   + ((size_t)27 * 64 * 128 * 2 + 255 & ~(size_t)255)   // wp1
                   + ((size_t)27 * 128 * 128 * 2 + 255 & ~(size_t)255)  // wp2
                   + ((size_t)64 * 128 * 2 + 255 & ~(size_t)255)        // wpPt
                   + 8192;                                              // slack
    int CB = 1;
    for (int cb = 8; cb >= 1; cb >>= 1) {
        size_t need = globals
                    + ((size_t)cb * R3_ * 64 * 4)     // voxC (aliases gC bf16)
                    + ((size_t)cb * R3_ * 64 * 2)     // gA
                    + ((size_t)cb * R3_ * 128 * 2)    // gB
                    + ((size_t)cb * N_ * 128 * 2)     // pf bf16
                    + ((size_t)cb * 64 * N_ * 2);     // featbc
        if (need <= ws_size) { CB = cb; break; }
    }

    char* ws = (char*)d_ws;
    size_t o = 0;
    auto alloc = [&](size_t bytes) {
        size_t r = o;
        o += (bytes + 255) & ~(size_t)255;
        return r;
    };
    float* voxC = (float*)(ws + alloc((size_t)CB * R3_ * 64 * 4));  // also gC bf16
    unsigned short* gC = (unsigned short*)voxC;
    unsigned short* gA = (unsigned short*)(ws + alloc((size_t)CB * R3_ * 64 * 2));
    unsigned short* gB = (unsigned short*)(ws + alloc((size_t)CB * R3_ * 128 * 2));
    unsigned short* pfbuf = (unsigned short*)(ws + alloc((size_t)CB * N_ * 128 * 2));
    unsigned short* featbc = (unsigned short*)(ws + alloc((size_t)CB * 64 * N_ * 2));
    float* cnt = (float*)(ws + alloc((size_t)B_ * R3_ * 4));
    float* ncoords = (float*)(ws + alloc((size_t)B_ * N_ * 3 * 4));
    int* flatidx = (int*)(ws + alloc((size_t)B_ * N_ * 4));
    float* bstats = (float*)(ws + alloc(256));
    float* statsAll = (float*)(ws + alloc(2048));
    float* stats1 = statsAll;
    float* stats2 = statsAll + 128;
    float* statsPt = statsAll + 256;
    unsigned short* wp1 = (unsigned short*)(ws + alloc((size_t)27 * 64 * 128 * 2));
    unsigned short* wp2 = (unsigned short*)(ws + alloc((size_t)27 * 128 * 128 * 2));
    unsigned short* wpPt = (unsigned short*)(ws + alloc((size_t)64 * 128 * 2));

    // ---- globals (once per launch)
    hipMemsetAsync(cnt, 0, (size_t)B_ * R3_ * 4, stream);
    hipMemsetAsync(statsAll, 0, 1536, stream);
    k_wpack16<<<(27 * 64 * 128 + 255) / 256, 256, 0, stream>>>(c1w, wp1, 64, 27);
    k_wpack16<<<(27 * 128 * 128 + 255) / 256, 256, 0, stream>>>(c2w, wp2, 128, 27);
    k_wpack16<<<(64 * 128 + 255) / 256, 256, 0, stream>>>(ptw, wpPt, 64, 1);
    k_batch_stats<<<B_, 256, 0, stream>>>(coords, bstats);
    k_points<<<B_ * N_ / 256, 256, 0, stream>>>(coords, bstats, ncoords, flatidx, cnt);

    // ---- per batch-chunk pipeline
    for (int b0 = 0; b0 < B_; b0 += CB) {
        hipMemsetAsync(voxC, 0, (size_t)CB * R3_ * 64 * 4, stream);
        k_feat2b<<<CB * 128, 256, 0, stream>>>(features, featbc, b0);
        k_scatter<<<CB * 64 * 16, 256, 0, stream>>>(features, flatidx, voxC, b0);
        k_divide<<<CB * 1024, 256, 0, stream>>>(voxC, cnt, gA, b0);
        k_conv16<64><<<CB * 256, 128, 0, stream>>>(gA, wp1, c1b, gB, stats1, b0);
        k_gnswish<<<CB * 2048, 256, 0, stream>>>(gB, stats1, g1g, g1b, b0);
        k_conv16<128><<<CB * 256, 128, 0, stream>>>(gB, wp2, c2b, gC, stats2, b0);
        k_point_mfma<<<CB * 16, 256, 0, stream>>>(featbc, wpPt, ptb, pfbuf, statsPt, b0);
        k_final<<<CB * 128, 256, 0, stream>>>(gC, ncoords, pfbuf,
                                              stats2, g2g, g2b, statsPt, pgg, pgb, outp, b0);
    }
}

// Round 9
// 617.322 us; speedup vs baseline: 1.2362x; 1.2362x over previous
//
#include <hip/hip_runtime.h>
#include <hip/hip_bf16.h>
#include <cstdint>

#define B_ 8
#define N_ 4096
#define CIN_ 64
#define COUT_ 128
#define R_ 32
#define R3_ 32768
#define GROUPS_ 8
#define EPS_ 1e-5f

typedef float f32x4 __attribute__((ext_vector_type(4)));
typedef __bf16 bf16x8 __attribute__((ext_vector_type(8)));
typedef unsigned short ushort8x __attribute__((ext_vector_type(8)));

static __device__ __forceinline__ unsigned short f2b(float f) {
    uint32_t u = __float_as_uint(f);
    uint32_t r = (u + 0x7fffu + ((u >> 16) & 1u)) >> 16;  // RNE
    return (unsigned short)r;
}
static __device__ __forceinline__ float b2f(unsigned short u) {
    return __uint_as_float(((uint32_t)u) << 16);
}
// fast swish via v_exp_f32 + v_rcp_f32 (bf16-accurate)
static __device__ __forceinline__ float fswish(float s) {
    return s * __builtin_amdgcn_rcpf(1.0f + __expf(-s));
}

// ---------------------------------------------------------------- batch stats
__global__ void k_batch_stats(const float* __restrict__ coords, float* __restrict__ bstats) {
    int b = blockIdx.x;
    int tid = threadIdx.x;
    __shared__ float rb[1024];
    __shared__ float smean[3];
    const float* cb = coords + (size_t)b * N_ * 3;
    float sx = 0.f, sy = 0.f, sz = 0.f;
    for (int n = tid; n < N_; n += 1024) {
        sx += cb[n * 3 + 0];
        sy += cb[n * 3 + 1];
        sz += cb[n * 3 + 2];
    }
    float vals[3] = {sx, sy, sz};
    for (int k = 0; k < 3; ++k) {
        rb[tid] = vals[k];
        __syncthreads();
        for (int s = 512; s > 0; s >>= 1) {
            if (tid < s) rb[tid] += rb[tid + s];
            __syncthreads();
        }
        if (tid == 0) smean[k] = rb[0] / (float)N_;
        __syncthreads();
    }
    float mx = smean[0], my = smean[1], mz = smean[2];
    float m2 = 0.f;
    for (int n = tid; n < N_; n += 1024) {
        float dx = cb[n * 3 + 0] - mx, dy = cb[n * 3 + 1] - my, dz = cb[n * 3 + 2] - mz;
        m2 = fmaxf(m2, dx * dx + dy * dy + dz * dz);
    }
    rb[tid] = m2;
    __syncthreads();
    for (int s = 512; s > 0; s >>= 1) {
        if (tid < s) rb[tid] = fmaxf(rb[tid], rb[tid + s]);
        __syncthreads();
    }
    if (tid == 0) {
        bstats[b * 4 + 0] = mx;
        bstats[b * 4 + 1] = my;
        bstats[b * 4 + 2] = mz;
        bstats[b * 4 + 3] = 2.0f * sqrtf(rb[0]);
    }
}

// -------------------------------------------------- per-point coords + counts
__global__ void k_points(const float* __restrict__ coords, const float* __restrict__ bstats,
                         float* __restrict__ ncoords, int* __restrict__ flatidx,
                         float* __restrict__ cnt) {
    int idx = blockIdx.x * 256 + threadIdx.x;  // b*N + n
    int b = idx >> 12, n = idx & (N_ - 1);
    float scale = bstats[b * 4 + 3];
    int vi[3];
    for (int k = 0; k < 3; ++k) {
        float c = coords[((size_t)b * N_ + n) * 3 + k] - bstats[b * 4 + k];
        float nc = fminf(fmaxf((c / scale + 0.5f) * (float)R_, 0.0f), (float)(R_ - 1));
        ncoords[((size_t)b * N_ + n) * 3 + k] = nc;
        vi[k] = (int)rintf(nc);  // round half-to-even, matches jnp.round
    }
    int flat = (vi[0] * R_ + vi[1]) * R_ + vi[2];
    flatidx[idx] = flat;
    atomicAdd(&cnt[(size_t)b * R3_ + flat], 1.0f);
}

// ------------------------------------------------------------- scatter (sum)
__global__ void k_scatter(const float* __restrict__ feat, const int* __restrict__ flatidx,
                          float* __restrict__ vox, int b0) {
    int bid = blockIdx.x;               // CB * 64ci * 16 chunks
    int nch = bid & 15, ci = (bid >> 4) & 63, bl = bid >> 10;
    int b = b0 + bl;
    int n = nch * 256 + threadIdx.x;
    float v = feat[((size_t)b * CIN_ + ci) * N_ + n];
    int flat = flatidx[b * N_ + n];
    atomicAdd(&vox[((size_t)bl * R3_ + flat) * CIN_ + ci], v);
}

// ----------------------------------- divide by counts, fp32 -> bf16 channels-last
__global__ void k_divide(const float* __restrict__ vox, const float* __restrict__ cnt,
                         unsigned short* __restrict__ gA, int b0) {
    size_t idx8 = (size_t)blockIdx.x * 256 + threadIdx.x;  // < cb*R3*8
    size_t voxel = idx8 >> 3;                              // bl*R3 + flat
    float c = cnt[(size_t)b0 * R3_ + voxel];
    float s = 1.0f / fmaxf(c, 1.0f);
    const float4* v4 = (const float4*)vox;
    float4 a = v4[idx8 * 2], b = v4[idx8 * 2 + 1];
    ushort8x o;
    o[0] = f2b(a.x * s); o[1] = f2b(a.y * s); o[2] = f2b(a.z * s); o[3] = f2b(a.w * s);
    o[4] = f2b(b.x * s); o[5] = f2b(b.y * s); o[6] = f2b(b.z * s); o[7] = f2b(b.w * s);
    ((ushort8x*)gA)[idx8] = o;
}

// ---------------------------------------- features fp32 -> bf16 (chunk-local)
__global__ void k_feat2b(const float* __restrict__ f, unsigned short* __restrict__ fb, int b0) {
    size_t i8 = (size_t)blockIdx.x * 256 + threadIdx.x;  // < CB*64*N/8
    const float4* s = (const float4*)(f + (size_t)b0 * CIN_ * N_);
    float4 a = s[i8 * 2], b = s[i8 * 2 + 1];
    ushort8x o;
    o[0] = f2b(a.x); o[1] = f2b(a.y); o[2] = f2b(a.z); o[3] = f2b(a.w);
    o[4] = f2b(b.x); o[5] = f2b(b.y); o[6] = f2b(b.z); o[7] = f2b(b.w);
    ((ushort8x*)fb)[i8] = o;
}

// --------------------- weight pack for 16x16x32 MFMA B-fragments
// wp element e = (((t*KC + kc)*8 + ct)*64 + l)*8 + j  holds
//   w[co = ct*16 + (l&15)][ci = kc*32 + (l>>4)*8 + j][t],  w layout [128][Cin][taps]
__global__ void k_wpack16(const float* __restrict__ w, unsigned short* __restrict__ wp,
                          int Cin, int taps) {
    int e = blockIdx.x * 256 + threadIdx.x;
    int total = taps * Cin * 128;
    if (e >= total) return;
    int KC = Cin / 32;
    int j = e & 7;
    int l = (e >> 3) & 63;
    int rest = e >> 9;
    int ct = rest & 7;
    int stepk = rest >> 3;  // t*KC + kc
    int kc = stepk % KC;
    int t = stepk / KC;
    int co = ct * 16 + (l & 15);
    int ci = kc * 32 + (l >> 4) * 8 + j;
    wp[e] = f2b(w[((size_t)co * Cin + ci) * taps + t]);
}

// --------------- GN apply + swish in-place on bf16 grid, A/B from raw stats
__global__ void k_gnswish(unsigned short* __restrict__ g, const float* __restrict__ stats,
                          const float* __restrict__ gamma, const float* __restrict__ beta,
                          int b0) {
    size_t idx8 = (size_t)blockIdx.x * 256 + threadIdx.x;  // < cb*R3*16
    int c0 = (int)(idx8 & 15) * 8;
    int b = b0 + (int)(idx8 >> 19);  // R3*128/8 = 2^19
    int grp = c0 >> 4;
    const float cntv = 16.0f * R3_;
    float mean = stats[(b * 8 + grp) * 2 + 0] / cntv;
    float var = stats[(b * 8 + grp) * 2 + 1] / cntv - mean * mean;
    float inv = rsqrtf(var + EPS_);
    ushort8x v = ((ushort8x*)g)[idx8];
#pragma unroll
    for (int k = 0; k < 8; ++k) {
        float A = gamma[c0 + k] * inv;
        float Bc = beta[c0 + k] - mean * A;
        v[k] = f2b(fswish(A * b2f(v[k]) + Bc));
    }
    ((ushort8x*)g)[idx8] = v;
}

// --------------------- implicit-GEMM 3x3x3 conv via bf16 MFMA 16x16x32
// R4 wave layout (best measured: 40% MfmaUtil) + zero-page LDS for 3 blocks/CU.
// in : [cb, R3, CIN] bf16 channels-last; out: [cb, R3, 128] bf16 (+bias); GN stats fused.
// block: 256 thr, covers (bl, x, 4 y-cols) = 128 voxels x 128 co.
// 4 waves = (y-pair yp, co-half ch); wave: 2x2 M-tiles (2y x 16z) x 4 N-tiles (64 co).
// LDS: 6 y-cols x 32 z rows (NO halo rows) + 1 shared zero row; A-reads clamp
// per-lane z in [-1,32] to the zero page. conv2: 52.5 KB -> 3 blocks/CU.
template <int CIN>
__global__ __launch_bounds__(256) void k_conv(
    const unsigned short* __restrict__ in, const unsigned short* __restrict__ wp,
    const float* __restrict__ bias, unsigned short* __restrict__ out,
    float* __restrict__ stats, int b0) {
    constexpr int KC = CIN / 32;
    constexpr int S = CIN + 8;       // row stride (bf16 elems), 16B-aligned rows
    constexpr int ZP = 6 * 32 * S;   // zero-page row offset (elems)
    __shared__ __align__(16) unsigned short abuf[(6 * 32 + 1) * S];
    __shared__ float s_sum[8], s_sq[8];
    int tid = threadIdx.x;
    int bid = blockIdx.x;
    int yg = bid & 7, x = (bid >> 3) & 31, bl = bid >> 8;
    int y0 = yg * 4;
    int lane = tid & 63, wv = tid >> 6;
    int yp = wv & 1, ch = wv >> 1;
    int mrow = lane & 15, quad = lane >> 4;

    if (tid < 8) { s_sum[tid] = 0.f; s_sq[tid] = 0.f; }
    // init the shared zero row (once)
    for (int i = tid; i < S / 8; i += 256) {
        ushort8x zz = {0, 0, 0, 0, 0, 0, 0, 0};
        *(ushort8x*)&abuf[ZP + i * 8] = zz;
    }

    float bv[4];
#pragma unroll
    for (int ct = 0; ct < 4; ++ct) bv[ct] = bias[ch * 64 + ct * 16 + mrow];
    f32x4 acc[2][2][4];
#pragma unroll
    for (int a = 0; a < 2; ++a)
#pragma unroll
        for (int zt = 0; zt < 2; ++zt)
#pragma unroll
            for (int ct = 0; ct < 4; ++ct) {
                acc[a][zt][ct][0] = bv[ct]; acc[a][zt][ct][1] = bv[ct];
                acc[a][zt][ct][2] = bv[ct]; acc[a][zt][ct][3] = bv[ct];
            }

    for (int xxi = 0; xxi < 3; ++xxi) {
        int xx = x + xxi - 1;
        if (xx < 0 || xx >= 32) continue;  // zero-pad: drop dx taps (block-uniform)
        __syncthreads();
        // stage 6 y-columns (32 z x CIN bf16 each) into rows cy*32 + z
        for (int i = tid; i < 6 * 32 * (CIN / 8); i += 256) {
            int cy = i / (32 * (CIN / 8));
            int r = i - cy * (32 * (CIN / 8));
            int z = r / (CIN / 8), c8 = r - z * (CIN / 8);
            int yy = y0 - 1 + cy;
            ushort8x v = {0, 0, 0, 0, 0, 0, 0, 0};
            if (yy >= 0 && yy < 32)
                v = *(const ushort8x*)&in[((size_t)bl * R3_ + xx * 1024 + yy * 32 + z) * CIN + c8 * 8];
            *(ushort8x*)&abuf[(cy * 32 + z) * S + c8 * 8] = v;
        }
        __syncthreads();

        for (int dy3 = 0; dy3 < 3; ++dy3) {
            for (int dz = 0; dz < 3; ++dz) {
                int t = (xxi * 3 + dy3) * 3 + dz;
#pragma unroll
                for (int kc = 0; kc < KC; ++kc) {
                    const unsigned short* wbase =
                        wp + ((size_t)((t * KC + kc) * 8 + ch * 4) * 64 + lane) * 8;
                    bf16x8 bfr[4];
#pragma unroll
                    for (int ct = 0; ct < 4; ++ct)
                        bfr[ct] = *(const bf16x8*)(wbase + ct * 512);
#pragma unroll
                    for (int yo2 = 0; yo2 < 2; ++yo2) {
                        int cy = yp * 2 + yo2 + dy3;
#pragma unroll
                        for (int zt = 0; zt < 2; ++zt) {
                            int z = zt * 16 + mrow + dz - 1;   // [-1, 32]
                            int off = (z >= 0 && z < 32)
                                          ? (cy * 32 + z) * S + kc * 32 + quad * 8
                                          : ZP + kc * 32 + quad * 8;
                            bf16x8 a = *(const bf16x8*)&abuf[off];
#pragma unroll
                            for (int ct = 0; ct < 4; ++ct)
                                acc[yo2][zt][ct] = __builtin_amdgcn_mfma_f32_16x16x32_bf16(
                                    a, bfr[ct], acc[yo2][zt][ct], 0, 0, 0);
                        }
                    }
                }
            }
        }
    }

    // store bf16 + GN stats. C/D: co = ch*64 + ct*16 + mrow, z = zt*16 + quad*4 + r
    float lsum[4] = {0.f, 0.f, 0.f, 0.f}, lsq[4] = {0.f, 0.f, 0.f, 0.f};
#pragma unroll
    for (int yo2 = 0; yo2 < 2; ++yo2) {
        int y = y0 + yp * 2 + yo2;
        unsigned short* obase = out + ((size_t)bl * R3_ + x * 1024 + y * 32) * 128;
#pragma unroll
        for (int zt = 0; zt < 2; ++zt) {
#pragma unroll
            for (int ct = 0; ct < 4; ++ct) {
                int co = ch * 64 + ct * 16 + mrow;
#pragma unroll
                for (int r = 0; r < 4; ++r) {
                    int z = zt * 16 + quad * 4 + r;
                    float vv = acc[yo2][zt][ct][r];
                    obase[(size_t)z * 128 + co] = f2b(vv);
                    lsum[ct] += vv;
                    lsq[ct] += vv * vv;
                }
            }
        }
    }
    // co = ch*64 + ct*16 + mrow -> group = ch*4 + ct (wave-uniform per ct)
#pragma unroll
    for (int ct = 0; ct < 4; ++ct) {
        float s = lsum[ct], q = lsq[ct];
#pragma unroll
        for (int off = 32; off >= 1; off >>= 1) {
            s += __shfl_xor(s, off);
            q += __shfl_xor(q, off);
        }
        if (lane == 0) {
            atomicAdd(&s_sum[ch * 4 + ct], s);
            atomicAdd(&s_sq[ch * 4 + ct], q);
        }
    }
    __syncthreads();
    if (tid < 8) {
        int b = b0 + bl;
        atomicAdd(&stats[((size_t)b * 8 + tid) * 2 + 0], s_sum[tid]);
        atomicAdd(&stats[((size_t)b * 8 + tid) * 2 + 1], s_sq[tid]);
    }
}

// ------------------- point transform 64->128 via MFMA, pf bf16 [n][co], + stats
__global__ __launch_bounds__(256) void k_point_mfma(
    const unsigned short* __restrict__ featb, const unsigned short* __restrict__ wp,
    const float* __restrict__ bias, unsigned short* __restrict__ pf,
    float* __restrict__ stats, int b0) {
    __shared__ __align__(16) unsigned short ALds[256 * 72];
    int tid = threadIdx.x;
    int bid = blockIdx.x;
    int bl = bid >> 4;
    int n0 = (bid & 15) * 256;
    int b = b0 + bl;
    int lane = tid & 63, wv = tid >> 6;
    int nh = wv & 1, ch = wv >> 1;
    int mrow = lane & 15, quad = lane >> 4;

    {
        int c0 = (tid >> 5) * 8;
        int nl = tid & 31;
        for (int u = 0; u < 8; ++u) {
            int n = u * 32 + nl;
            ushort8x v;
#pragma unroll
            for (int k = 0; k < 8; ++k)
                v[k] = featb[((size_t)(bl * 64 + c0 + k)) * N_ + n0 + n];
            *(ushort8x*)&ALds[n * 72 + c0] = v;
        }
    }

    bf16x8 bfr[2][4];
#pragma unroll
    for (int kc = 0; kc < 2; ++kc)
#pragma unroll
        for (int ct = 0; ct < 4; ++ct)
            bfr[kc][ct] = *(const bf16x8*)&wp[((size_t)((kc * 8) + ch * 4 + ct) * 64 + lane) * 8];

    float bv[4];
#pragma unroll
    for (int ct = 0; ct < 4; ++ct) bv[ct] = bias[ch * 64 + ct * 16 + mrow];
    f32x4 acc[8][4];
#pragma unroll
    for (int mt = 0; mt < 8; ++mt)
#pragma unroll
        for (int ct = 0; ct < 4; ++ct) {
            acc[mt][ct][0] = bv[ct]; acc[mt][ct][1] = bv[ct];
            acc[mt][ct][2] = bv[ct]; acc[mt][ct][3] = bv[ct];
        }

    __syncthreads();
#pragma unroll
    for (int kc = 0; kc < 2; ++kc) {
#pragma unroll
        for (int mt = 0; mt < 8; ++mt) {
            bf16x8 a = *(const bf16x8*)
                &ALds[(nh * 128 + mt * 16 + mrow) * 72 + kc * 32 + quad * 8];
#pragma unroll
            for (int ct = 0; ct < 4; ++ct)
                acc[mt][ct] = __builtin_amdgcn_mfma_f32_16x16x32_bf16(
                    a, bfr[kc][ct], acc[mt][ct], 0, 0, 0);
        }
    }

#pragma unroll
    for (int ct = 0; ct < 4; ++ct) {
        int co = ch * 64 + ct * 16 + mrow;
        float s = 0.f, q = 0.f;
#pragma unroll
        for (int mt = 0; mt < 8; ++mt) {
#pragma unroll
            for (int r = 0; r < 4; ++r) {
                int n = nh * 128 + mt * 16 + quad * 4 + r;
                float vv = acc[mt][ct][r];
                pf[((size_t)bl * N_ + n0 + n) * 128 + co] = f2b(vv);
                s += vv;
                q += vv * vv;
            }
        }
#pragma unroll
        for (int off = 32; off >= 1; off >>= 1) {
            s += __shfl_xor(s, off);
            q += __shfl_xor(q, off);
        }
        if (lane == 0) {
            int g = ch * 4 + ct;
            atomicAdd(&stats[((size_t)b * 8 + g) * 2 + 0], s);
            atomicAdd(&stats[((size_t)b * 8 + g) * 2 + 1], q);
        }
    }
}

// ------ trilinear devoxelize (GN2+swish fused per gather) + point GN/swish + add
__global__ __launch_bounds__(256) void k_final(
    const unsigned short* __restrict__ grid, const float* __restrict__ ncoords,
    const unsigned short* __restrict__ pf,
    const float* __restrict__ stats2, const float* __restrict__ g2g,
    const float* __restrict__ g2b,
    const float* __restrict__ statsPt, const float* __restrict__ pgg,
    const float* __restrict__ pgb,
    float* __restrict__ out, int b0) {
    __shared__ int sidx[32][8];
    __shared__ float swt[32][8];
    __shared__ float devt[32 * 129];
    int bid = blockIdx.x;
    int bl = bid >> 7;
    int b = b0 + bl;
    int n0 = (bid & 127) * 32;
    int tid = threadIdx.x;
    if (tid < 32) {
        int n = n0 + tid;
        const float* nc = ncoords + ((size_t)b * N_ + n) * 3;
        float fc[3] = {nc[0], nc[1], nc[2]};
        int i0[3], i1[3];
        float dd[3];
        for (int k = 0; k < 3; ++k) {
            float fl = floorf(fc[k]);
            i0[k] = (int)fl;
            i1[k] = min(i0[k] + 1, R_ - 1);
            dd[k] = fc[k] - fl;
        }
#pragma unroll
        for (int k = 0; k < 8; ++k) {
            int ix = (k >> 2) & 1, iy = (k >> 1) & 1, iz = k & 1;
            int xi = ix ? i1[0] : i0[0];
            int yi = iy ? i1[1] : i0[1];
            int zi = iz ? i1[2] : i0[2];
            sidx[tid][k] = (xi * R_ + yi) * R_ + zi;
            float wx = ix ? dd[0] : 1.0f - dd[0];
            float wy = iy ? dd[1] : 1.0f - dd[1];
            float wz = iz ? dd[2] : 1.0f - dd[2];
            swt[tid][k] = wx * wy * wz;
        }
    }
    __syncthreads();
    int co = tid & 127, pg = tid >> 7;
    int grp = co >> 4;
    const float ic2 = 1.0f / (16.0f * R3_);
    float mean2 = stats2[(b * 8 + grp) * 2 + 0] * ic2;
    float var2 = stats2[(b * 8 + grp) * 2 + 1] * ic2 - mean2 * mean2;
    float inv2 = rsqrtf(var2 + EPS_);
    float A2 = g2g[co] * inv2, B2 = g2b[co] - mean2 * A2;
    const float icp = 1.0f / (16.0f * N_);
    float meanp = statsPt[(b * 8 + grp) * 2 + 0] * icp;
    float varp = statsPt[(b * 8 + grp) * 2 + 1] * icp - meanp * meanp;
    float invp = rsqrtf(varp + EPS_);
    float Ap = pgg[co] * invp, Bp = pgb[co] - meanp * Ap;

    const unsigned short* gp = grid + (size_t)bl * R3_ * 128 + co;
    for (int p = pg; p < 32; p += 2) {
        float acc = 0.f;
#pragma unroll
        for (int k = 0; k < 8; ++k) {
            float s = A2 * b2f(gp[(size_t)sidx[p][k] * 128]) + B2;
            acc += swt[p][k] * fswish(s);
        }
        float xv = b2f(pf[((size_t)bl * N_ + n0 + p) * 128 + co]);
        devt[p * 129 + co] = acc + fswish(Ap * xv + Bp);
    }
    __syncthreads();
    int pp = tid & 31, cg = tid >> 5;
    float* op = out + (size_t)b * 128 * N_ + n0 + pp;
    for (int c = cg * 16; c < cg * 16 + 16; ++c)
        op[(size_t)c * N_] = devt[pp * 129 + c];
}

extern "C" void kernel_launch(void* const* d_in, const int* in_sizes, int n_in,
                              void* d_out, int out_size, void* d_ws, size_t ws_size,
                              hipStream_t stream) {
    const float* features = (const float*)d_in[0];
    const float* coords = (const float*)d_in[1];
    const float* c1w = (const float*)d_in[2];
    const float* c1b = (const float*)d_in[3];
    const float* g1g = (const float*)d_in[4];
    const float* g1b = (const float*)d_in[5];
    const float* c2w = (const float*)d_in[6];
    const float* c2b = (const float*)d_in[7];
    const float* g2g = (const float*)d_in[8];
    const float* g2b = (const float*)d_in[9];
    const float* ptw = (const float*)d_in[10];
    const float* ptb = (const float*)d_in[11];
    const float* pgg = (const float*)d_in[12];
    const float* pgb = (const float*)d_in[13];
    float* outp = (float*)d_out;

    size_t globals = ((size_t)B_ * R3_ * 4 + 255 & ~(size_t)255)        // cnt
                   + ((size_t)B_ * N_ * 3 * 4 + 255 & ~(size_t)255)     // ncoords
                   + ((size_t)B_ * N_ * 4 + 255 & ~(size_t)255)         // flatidx
                   + 256 + 2048                                         // bstats, statsAll
                   + ((size_t)27 * 64 * 128 * 2 + 255 & ~(size_t)255)   // wp1
                   + ((size_t)27 * 128 * 128 * 2 + 255 & ~(size_t)255)  // wp2
                   + ((size_t)64 * 128 * 2 + 255 & ~(size_t)255)        // wpPt
                   + 8192;                                              // slack
    int CB = 1;
    for (int cb = 8; cb >= 1; cb >>= 1) {
        size_t need = globals
                    + ((size_t)cb * R3_ * 64 * 4)     // voxC (aliases gC bf16)
                    + ((size_t)cb * R3_ * 64 * 2)     // gA
                    + ((size_t)cb * R3_ * 128 * 2)    // gB
                    + ((size_t)cb * N_ * 128 * 2)     // pf bf16
                    + ((size_t)cb * 64 * N_ * 2);     // featbc
        if (need <= ws_size) { CB = cb; break; }
    }

    char* ws = (char*)d_ws;
    size_t o = 0;
    auto alloc = [&](size_t bytes) {
        size_t r = o;
        o += (bytes + 255) & ~(size_t)255;
        return r;
    };
    float* voxC = (float*)(ws + alloc((size_t)CB * R3_ * 64 * 4));  // also gC bf16
    unsigned short* gC = (unsigned short*)voxC;
    unsigned short* gA = (unsigned short*)(ws + alloc((size_t)CB * R3_ * 64 * 2));
    unsigned short* gB = (unsigned short*)(ws + alloc((size_t)CB * R3_ * 128 * 2));
    unsigned short* pfbuf = (unsigned short*)(ws + alloc((size_t)CB * N_ * 128 * 2));
    unsigned short* featbc = (unsigned short*)(ws + alloc((size_t)CB * 64 * N_ * 2));
    float* cnt = (float*)(ws + alloc((size_t)B_ * R3_ * 4));
    float* ncoords = (float*)(ws + alloc((size_t)B_ * N_ * 3 * 4));
    int* flatidx = (int*)(ws + alloc((size_t)B_ * N_ * 4));
    float* bstats = (float*)(ws + alloc(256));
    float* statsAll = (float*)(ws + alloc(2048));
    float* stats1 = statsAll;
    float* stats2 = statsAll + 128;
    float* statsPt = statsAll + 256;
    unsigned short* wp1 = (unsigned short*)(ws + alloc((size_t)27 * 64 * 128 * 2));
    unsigned short* wp2 = (unsigned short*)(ws + alloc((size_t)27 * 128 * 128 * 2));
    unsigned short* wpPt = (unsigned short*)(ws + alloc((size_t)64 * 128 * 2));

    // ---- globals (once per launch)
    hipMemsetAsync(cnt, 0, (size_t)B_ * R3_ * 4, stream);
    hipMemsetAsync(statsAll, 0, 1536, stream);
    k_wpack16<<<(27 * 64 * 128 + 255) / 256, 256, 0, stream>>>(c1w, wp1, 64, 27);
    k_wpack16<<<(27 * 128 * 128 + 255) / 256, 256, 0, stream>>>(c2w, wp2, 128, 27);
    k_wpack16<<<(64 * 128 + 255) / 256, 256, 0, stream>>>(ptw, wpPt, 64, 1);
    k_batch_stats<<<B_, 1024, 0, stream>>>(coords, bstats);
    k_points<<<B_ * N_ / 256, 256, 0, stream>>>(coords, bstats, ncoords, flatidx, cnt);

    // ---- per batch-chunk pipeline
    for (int b0 = 0; b0 < B_; b0 += CB) {
        hipMemsetAsync(voxC, 0, (size_t)CB * R3_ * 64 * 4, stream);
        k_feat2b<<<CB * 128, 256, 0, stream>>>(features, featbc, b0);
        k_scatter<<<CB * 64 * 16, 256, 0, stream>>>(features, flatidx, voxC, b0);
        k_divide<<<CB * 1024, 256, 0, stream>>>(voxC, cnt, gA, b0);
        k_conv<64><<<CB * 256, 256, 0, stream>>>(gA, wp1, c1b, gB, stats1, b0);
        k_gnswish<<<CB * 2048, 256, 0, stream>>>(gB, stats1, g1g, g1b, b0);
        k_conv<128><<<CB * 256, 256, 0, stream>>>(gB, wp2, c2b, gC, stats2, b0);
        k_point_mfma<<<CB * 16, 256, 0, stream>>>(featbc, wpPt, ptb, pfbuf, statsPt, b0);
        k_final<<<CB * 128, 256, 0, stream>>>(gC, ncoords, pfbuf,
                                              stats2, g2g, g2b, statsPt, pgg, pgb, outp, b0);
    }
}